// Round 9
// baseline (252.683 us; speedup 1.0000x reference)
//
#include <hip/hip_runtime.h>
#include <hip/hip_fp16.h>
#include <stdint.h>

#define TOK 8192      // B*S
#define DIM 1024
#define NE 8
#define NT 72         // max 256-row tiles: 64 full + <=7 ragged (+1 safety)
#define NCT 4         // 1024 / 256 col-tiles

typedef short bf16x8 __attribute__((ext_vector_type(8)));
typedef float f32x4 __attribute__((ext_vector_type(4)));

__device__ __forceinline__ unsigned short f2bf(float f) {
  unsigned int u = __float_as_uint(f);
  u += 0x7FFFu + ((u >> 16) & 1u);
  return (unsigned short)(u >> 16);
}

__device__ __forceinline__ void gl_lds16(const void* g, void* l) {
  __builtin_amdgcn_global_load_lds(
      (__attribute__((address_space(1))) unsigned int*)(g),
      (__attribute__((address_space(3))) unsigned int*)(l), 16, 0, 0);
}

__device__ __forceinline__ unsigned lds_off(const void* p) {
  return (unsigned)(size_t)(__attribute__((address_space(3))) const void*)p;
}

// Three fused aux branches: [0,2048) gate, [2048,4096) W-transpose,
// [4096,6144) zero-out (atomic-combine needs out pre-zeroed; done here two
// kernels before moe_gemm, stream-ordered).
__global__ __launch_bounds__(256) void gate_transpose(
    const float* __restrict__ x, const float* __restrict__ gW,
    const float* __restrict__ gb, unsigned short* __restrict__ xb,
    int* __restrict__ eSel, float* __restrict__ wSel, int* __restrict__ cnt,
    const float* __restrict__ W, unsigned short* __restrict__ Wt,
    float4* __restrict__ outz)
{
  __shared__ __align__(16) float smem[NE * DIM];   // 32 KB union

  if (blockIdx.x >= 4096) {
    // ---- zero branch: 2048 blocks x 16 KB = 32 MB
    const float4 z = {0.f, 0.f, 0.f, 0.f};
    const unsigned base = (blockIdx.x - 4096) * 256 + threadIdx.x;
#pragma unroll
    for (int h = 0; h < 4; ++h)
      outz[base + h * 524288] = z;     // 2M float4 total
    return;
  }

  if (blockIdx.x >= 2048) {
    // ---- transpose_w branch: expert_W [e][d][f] fp32 -> Wt [e][f][d] bf16
    float (*t2)[65] = (float(*)[65])smem;          // 64 x 65 padded
    const int b  = blockIdx.x - 2048;
    const int e  = b >> 8;                 // 256 tiles per expert
    const int db = (b >> 4) & 15;          // d (k) block
    const int fb = b & 15;                 // f block
    const int d0 = db * 64, f0 = fb * 64;
    const int tid = threadIdx.x;
#pragma unroll
    for (int h = 0; h < 4; ++h) {
      const int idx = tid + h * 256;
      const int r = idx >> 4, c4 = idx & 15;
      float4 v = *(const float4*)&W[((size_t)e * DIM + d0 + r) * DIM + f0 + c4 * 4];
      t2[r][c4 * 4 + 0] = v.x;
      t2[r][c4 * 4 + 1] = v.y;
      t2[r][c4 * 4 + 2] = v.z;
      t2[r][c4 * 4 + 3] = v.w;
    }
    __syncthreads();
#pragma unroll
    for (int h = 0; h < 8; ++h) {
      const int o = tid + h * 256;
      const int f = o >> 5, k2 = (o & 31) * 2;
      const unsigned int lo = f2bf(t2[k2][f]);
      const unsigned int hi = f2bf(t2[k2 + 1][f]);
      *(unsigned int*)&Wt[((size_t)e * DIM + f0 + f) * DIM + d0 + k2] =
          lo | (hi << 16);
    }
    return;
  }

  // ---- gate branch: x row -> bf16 + gating dots (fp64 acc) + top-2 picks
  if (blockIdx.x == 0 && threadIdx.x < NE) cnt[threadIdx.x] = 0;

  float* gWs = smem;                // [e][d], 32 KB
#pragma unroll
  for (int h = 0; h < 8; ++h) {
    const int m = threadIdx.x + h * 256;       // float4 id over gW (2048)
    float4 v = ((const float4*)gW)[m];
    const int d = m >> 1, e0 = (m & 1) * 4;    // gW is [d][e]
    gWs[(e0 + 0) * DIM + d] = v.x;
    gWs[(e0 + 1) * DIM + d] = v.y;
    gWs[(e0 + 2) * DIM + d] = v.z;
    gWs[(e0 + 3) * DIM + d] = v.w;
  }
  __syncthreads();

  const int wave = threadIdx.x >> 6;
  const int lane = threadIdx.x & 63;
  const int t = blockIdx.x * 4 + wave;
  const float4* xrow = (const float4*)(x + (size_t)t * DIM);
  ushort4* xbrow = (ushort4*)(xb + (size_t)t * DIM);

  double acc[NE];
#pragma unroll
  for (int e = 0; e < NE; ++e) acc[e] = 0.0;

#pragma unroll
  for (int i = 0; i < 4; ++i) {
    const int j = i * 64 + lane;         // float4 index within row (0..255)
    float4 v = xrow[j];
    ushort4 pk;
    pk.x = f2bf(v.x); pk.y = f2bf(v.y); pk.z = f2bf(v.z); pk.w = f2bf(v.w);
    xbrow[j] = pk;
#pragma unroll
    for (int e = 0; e < NE; ++e) {
      float4 gv = *(const float4*)&gWs[e * DIM + j * 4];
      acc[e] += (double)v.x * (double)gv.x + (double)v.y * (double)gv.y
              + (double)v.z * (double)gv.z + (double)v.w * (double)gv.w;
    }
  }
#pragma unroll
  for (int off = 32; off > 0; off >>= 1) {
#pragma unroll
    for (int e = 0; e < NE; ++e)
      acc[e] += __shfl_xor(acc[e], off, 64);
  }

  if (lane == 0) {
    double s[NE];
#pragma unroll
    for (int e = 0; e < NE; ++e) {
      s[e] = acc[e] + (double)gb[e];
      if (s[e] < 1e-4) s[e] = 1e-4;     // clamp-min(EPS), TEMP=1
    }
    int e0 = 0;
    for (int e = 1; e < NE; ++e) if (s[e] > s[e0]) e0 = e;
    int e1 = (e0 == 0) ? 1 : 0;
    for (int e = 0; e < NE; ++e) if (e != e0 && s[e] > s[e1]) e1 = e;
    float m = (float)s[e0];
    float Z = 0.f, pf[NE];
#pragma unroll
    for (int e = 0; e < NE; ++e) { pf[e] = __expf((float)s[e] - m); Z += pf[e]; }
    float w0 = pf[e0] / Z; if (w0 < 0.1f) w0 = 0.1f;
    float w1 = pf[e1] / Z; if (w1 < 0.1f) w1 = 0.1f;
    const float inv = 0.5f / (w0 + w1);   // /total /K
    eSel[t * 2 + 0] = e0;
    eSel[t * 2 + 1] = e1;
    wSel[t * 2 + 0] = w0 * inv;
    wSel[t * 2 + 1] = w1 * inv;
  }
}

// Two-level scatter: LDS histogram per block, 8 global atomics per block.
__global__ __launch_bounds__(256) void scatter_kernel(
    const int* __restrict__ eSel, const float* __restrict__ wSel,
    int* __restrict__ cnt, int* __restrict__ listTok, float* __restrict__ listW)
{
  __shared__ int lcnt[NE];
  __shared__ int base[NE];
  const int tid = threadIdx.x;
  if (tid < NE) lcnt[tid] = 0;
  __syncthreads();

  const int t = blockIdx.x * 256 + tid;
  const int e0 = eSel[t * 2 + 0];
  const int e1 = eSel[t * 2 + 1];
  const float w0 = wSel[t * 2 + 0];
  const float w1 = wSel[t * 2 + 1];
  const int l0 = atomicAdd(&lcnt[e0], 1);
  const int l1 = atomicAdd(&lcnt[e1], 1);
  __syncthreads();
  if (tid < NE) base[tid] = atomicAdd(&cnt[tid], lcnt[tid]);
  __syncthreads();

  const int p0 = base[e0] + l0;
  listTok[e0 * TOK + p0] = t * 2 + 0;   // token*2 + slot
  listW [e0 * TOK + p0] = w0;
  const int p1 = base[e1] + l1;
  listTok[e1 * TOK + p1] = t * 2 + 1;
  listW [e1 * TOK + p1] = w1;
}

// ---------------------------------------------------------------------------
// R15 moe_gemm: R14 geometry (256x256 tile, 8 waves, 128x64 wave-tile) with
// TWO fixes from the closed cycle model (R14: 2625 cy/iter measured = LDS
// 1152+256 + MFMA 1242 fully SERIALIZED by the in-wave read->wait->MFMA
// order):
//  1. Register double-buffered fragments: iter kt ISSUES tile kt+1's 12
//     ds_reads (asm, no wait) before MFMA(tile kt); reads complete under the
//     ~620cy MFMA shadow -> LDS and MFMA pipes overlap. Needs ring-4 LDS
//     (130KB, prefetch-3) so tile kt+1 is resident when its reads issue.
//     Floor drops 2625 -> ~1400 cy/iter.
//  2. Combine fused: epilogue does unsafeAtomicAdd fp32 into out (native
//     global_atomic_add_f32); out pre-zeroed by gate_transpose's 3rd branch.
//     Kills the separate 96MB combine pass + one launch drain.
// Ring-4 invariant (per wave, 4 gl_lds16/tile): at START of iter kt, tiles
// <= kt+1 resident, tile kt+2's 4 calls outstanding. Body: STG(kt+3) -> 8
// outstanding; end-of-iter vmcnt(4) retires kt+2. Reads of slot (kt+1)&3 at
// iter kt are 2 barriers ahead of that slot's overwrite (STG kt+5 at iter
// kt+2). Unroll-4 (slots compile-time) x alternating frag sets E/O
// (rule #20: no runtime-indexed reg arrays).
// ---------------------------------------------------------------------------
#define WAITVM(n) asm volatile("s_waitcnt vmcnt(" #n ")" ::: "memory")
#define WAITLGKM  { asm volatile("s_waitcnt lgkmcnt(0)" ::: "memory"); \
                    __builtin_amdgcn_sched_barrier(0); }

#define STG(kt, bs)                                                          \
  { const int off_ = (kt) * 32;                                              \
    gl_lds16(srcA0 + off_, &As[bs][w * 512]);                                \
    gl_lds16(srcA1 + off_, &As[bs][128 * 32 + w * 512]);                     \
    gl_lds16(srcB0 + off_, &Bs[bs][w * 512]);                                \
    gl_lds16(srcB1 + off_, &Bs[bs][128 * 32 + w * 512]); }

// Issue 12 ds_read_b128 into frag set P (no wait). sched_barrier pins the
// following MFMAs after the issue (they'd otherwise be hoist-legal).
#define RD(P, bs)                                                            \
  { const unsigned aA = asOff + (unsigned)(bs) * 16384u + rdA2;              \
    const unsigned bA = bsOff + (unsigned)(bs) * 16384u + rdB2;              \
    asm volatile(                                                            \
      "ds_read_b128 %0, %12 offset:0\n\t"                                    \
      "ds_read_b128 %1, %12 offset:1024\n\t"                                 \
      "ds_read_b128 %2, %12 offset:2048\n\t"                                 \
      "ds_read_b128 %3, %12 offset:3072\n\t"                                 \
      "ds_read_b128 %4, %12 offset:4096\n\t"                                 \
      "ds_read_b128 %5, %12 offset:5120\n\t"                                 \
      "ds_read_b128 %6, %12 offset:6144\n\t"                                 \
      "ds_read_b128 %7, %12 offset:7168\n\t"                                 \
      "ds_read_b128 %8, %13 offset:0\n\t"                                    \
      "ds_read_b128 %9, %13 offset:1024\n\t"                                 \
      "ds_read_b128 %10, %13 offset:2048\n\t"                                \
      "ds_read_b128 %11, %13 offset:3072"                                    \
      : "=&v"(P##a0),"=&v"(P##a1),"=&v"(P##a2),"=&v"(P##a3),                 \
        "=&v"(P##a4),"=&v"(P##a5),"=&v"(P##a6),"=&v"(P##a7),                 \
        "=&v"(P##b0),"=&v"(P##b1),"=&v"(P##b2),"=&v"(P##b3)                  \
      : "v"(aA), "v"(bA)                                                     \
      : "memory");                                                           \
    __builtin_amdgcn_sched_barrier(0); }

#define MM(P)                                                                \
  { bf16x8 af[8] = {P##a0, P##a1, P##a2, P##a3, P##a4, P##a5, P##a6, P##a7}; \
    bf16x8 bfv[4] = {P##b0, P##b1, P##b2, P##b3};                            \
    __builtin_amdgcn_s_setprio(1);                                           \
    _Pragma("unroll")                                                        \
    for (int mt = 0; mt < 8; ++mt)                                           \
      _Pragma("unroll")                                                      \
      for (int nt = 0; nt < 4; ++nt)                                         \
        acc[mt][nt] = __builtin_amdgcn_mfma_f32_16x16x32_bf16(               \
            af[mt], bfv[nt], acc[mt][nt], 0, 0, 0);                          \
    __builtin_amdgcn_s_setprio(0); }

#define BAR __builtin_amdgcn_s_barrier()

__global__ __launch_bounds__(512, 2) void moe_gemm(
    const unsigned short* __restrict__ xb, const unsigned short* __restrict__ Wt,
    const float* __restrict__ eb, const int* __restrict__ cnt,
    const int* __restrict__ listTok, const float* __restrict__ listW,
    float* __restrict__ out)
{
  const int dId = blockIdx.x % NT;   // dId-major; cT siblings share XCD
  const int cT  = blockIdx.x / NT;
  int e = -1, r0 = 0, rows = 0, accT = 0;
#pragma unroll
  for (int ee = 0; ee < NE; ++ee) {
    const int c = cnt[ee];
    const int nt = (c + 255) >> 8;
    if (dId >= accT && dId < accT + nt) {
      e = ee; r0 = (dId - accT) * 256;
      rows = c - r0; if (rows > 256) rows = 256;
    }
    accT += nt;
  }
  if (e < 0) return;   // block-uniform exit, before any barrier

  // ring-4: A 4x16KB + B 4x16KB + lists 2KB = 130KB -> 1 block/CU, 8 waves
  __shared__ __align__(16) unsigned short As[4][256 * 32];
  __shared__ __align__(16) unsigned short Bs[4][256 * 32];
  __shared__ int   tid_s[256];
  __shared__ float w_s[256];

  const int tid = threadIdx.x;
  if (tid < 256) {
    if (tid < rows) {
      tid_s[tid] = listTok[e * TOK + r0 + tid];
      w_s[tid]   = listW [e * TOK + r0 + tid];
    } else {
      tid_s[tid] = 0;   // safe dummy row (token 0) — never stored
      w_s[tid]   = 0.0f;
    }
  }
  __syncthreads();      // drains vmcnt -> counted region starts clean

  const int w    = tid >> 6;           // wave 0..7
  const int lane = tid & 63;
  const int qsrc = (lane & 3) ^ ((lane >> 3) & 3);
  const int lr   = lane >> 2;
  const unsigned short* srcA0 = xb + (size_t)(tid_s[      w * 16 + lr] >> 1) * DIM + qsrc * 8;
  const unsigned short* srcA1 = xb + (size_t)(tid_s[128 + w * 16 + lr] >> 1) * DIM + qsrc * 8;
  const size_t bbase = ((size_t)e * DIM + cT * 256) * DIM;
  const unsigned short* srcB0 = Wt + bbase + (size_t)(      w * 16 + lr) * DIM + qsrc * 8;
  const unsigned short* srcB1 = Wt + bbase + (size_t)(128 + w * 16 + lr) * DIM + qsrc * 8;

  const int wr = w >> 2, wc = w & 3;   // 2M x 4N wave grid, 128x64 out each
  const int mrow = lane & 15;
  const int qg   = lane >> 4;
  const int s8   = (qg ^ ((mrow >> 1) & 3)) * 8;   // verified conflict-free
  const unsigned rdA2 = (unsigned)(((wr * 128 + mrow) * 32 + s8) * 2);  // bytes
  const unsigned rdB2 = (unsigned)(((wc * 64 + mrow) * 32 + s8) * 2);   // bytes
  const unsigned asOff = lds_off(&As[0][0]);
  const unsigned bsOff = lds_off(&Bs[0][0]);

  f32x4 acc[8][4];
#pragma unroll
  for (int i = 0; i < 8; ++i)
#pragma unroll
    for (int j = 0; j < 4; ++j)
      acc[i][j] = {0.f, 0.f, 0.f, 0.f};

  // frag sets E (even kt) and O (odd kt)
  bf16x8 Ea0,Ea1,Ea2,Ea3,Ea4,Ea5,Ea6,Ea7,Eb0,Eb1,Eb2,Eb3;
  bf16x8 Oa0,Oa1,Oa2,Oa3,Oa4,Oa5,Oa6,Oa7,Ob0,Ob1,Ob2,Ob3;

  // prologue: tiles 0,1,2 -> slots 0,1,2; retire 0,1; read tile 0 into E
  STG(0, 0); STG(1, 1); STG(2, 2);
  WAITVM(4);
  BAR;
  RD(E, 0);
  WAITLGKM;

#pragma unroll 1
  for (int t = 0; t < 7; ++t) {        // kt = 4t .. 4t+3 (0..27)
    const int k4 = t * 4;
    STG(k4 + 3, 3); RD(O, 1); MM(E); WAITLGKM; WAITVM(4); BAR;
    STG(k4 + 4, 0); RD(E, 2); MM(O); WAITLGKM; WAITVM(4); BAR;
    STG(k4 + 5, 1); RD(O, 3); MM(E); WAITLGKM; WAITVM(4); BAR;
    STG(k4 + 6, 2); RD(E, 0); MM(O); WAITLGKM; WAITVM(4); BAR;
  }
  // kt=28..31 tail
  STG(31, 3); RD(O, 1); MM(E); WAITLGKM; WAITVM(4); BAR;   // kt=28
  RD(E, 2); MM(O); WAITLGKM; WAITVM(0); BAR;               // kt=29
  RD(O, 3); MM(E); WAITLGKM;                               // kt=30
  MM(O);                                                   // kt=31

  // epilogue: C/D map col=lane&15, row=(lane>>4)*4+r; fused combine via
  // native fp32 atomic add (out pre-zeroed). Both expert slots of a token
  // add into the same row.
  const int colBase = cT * 256 + wc * 64 + mrow;
  float bias[4];
#pragma unroll
  for (int nt = 0; nt < 4; ++nt)
    bias[nt] = eb[(size_t)e * DIM + colBase + nt * 16];
#pragma unroll
  for (int mt = 0; mt < 8; ++mt) {
#pragma unroll
    for (int r = 0; r < 4; ++r) {
      const int rloc = wr * 128 + mt * 16 + (lane >> 4) * 4 + r;
      if (rloc < rows) {
        const int tk    = tid_s[rloc];
        const float wgt = w_s[rloc];
        float* dst = out + (size_t)(tk >> 1) * DIM;
#pragma unroll
        for (int nt = 0; nt < 4; ++nt)
          unsafeAtomicAdd(&dst[colBase + nt * 16],
                          wgt * (acc[mt][nt][r] + bias[nt]));
      }
    }
  }
}

extern "C" void kernel_launch(void* const* d_in, const int* in_sizes, int n_in,
                              void* d_out, int out_size, void* d_ws, size_t ws_size,
                              hipStream_t stream)
{
  const float* x  = (const float*)d_in[0];
  const float* gW = (const float*)d_in[1];
  const float* gb = (const float*)d_in[2];
  const float* eW = (const float*)d_in[3];
  const float* eb = (const float*)d_in[4];
  float* out = (float*)d_out;

  char* p = (char*)d_ws;
  unsigned short* xb = (unsigned short*)p;  p += (size_t)TOK * DIM * 2;       // 16 MB
  unsigned short* Wt = (unsigned short*)p;  p += (size_t)NE * DIM * DIM * 2;  // 16 MB
  char* scratch = p;                        p += (size_t)2 * TOK * DIM * 2;   // 32 MB (eSel/wSel live here)
  int* cnt = (int*)p;                       p += 256;
  int* listTok = (int*)p;                   p += (size_t)NE * TOK * 4;
  float* listW = (float*)p;                 p += (size_t)NE * TOK * 4;

  int*   eSel = (int*)scratch;                      // TOK*2 ints = 64 KB
  float* wSel = (float*)(scratch + TOK * 8);        // TOK*2 floats = 64 KB

  gate_transpose<<<6144, 256, 0, stream>>>(x, gW, gb, xb, eSel, wSel, cnt,
                                           eW, Wt, (float4*)out);
  scatter_kernel<<<TOK / 256, 256, 0, stream>>>(eSel, wSel, cnt, listTok, listW);
  moe_gemm<<<NT * NCT, 512, 0, stream>>>(xb, Wt, eb, cnt, listTok, listW, out);
}

// Round 10
// 222.083 us; speedup vs baseline: 1.1378x; 1.1378x over previous
//
#include <hip/hip_runtime.h>
#include <hip/hip_fp16.h>
#include <stdint.h>

#define TOK 8192      // B*S
#define DIM 1024
#define NE 8
#define NT 72         // max 256-row tiles: 64 full + <=7 ragged (+1 safety)
#define NCT 8         // 1024 / 128 col-tiles

typedef short bf16x8 __attribute__((ext_vector_type(8)));
typedef float f32x4 __attribute__((ext_vector_type(4)));

__device__ __forceinline__ unsigned short f2bf(float f) {
  unsigned int u = __float_as_uint(f);
  u += 0x7FFFu + ((u >> 16) & 1u);
  return (unsigned short)(u >> 16);
}

__device__ __forceinline__ void gl_lds16(const void* g, void* l) {
  __builtin_amdgcn_global_load_lds(
      (__attribute__((address_space(1))) unsigned int*)(g),
      (__attribute__((address_space(3))) unsigned int*)(l), 16, 0, 0);
}

__device__ __forceinline__ unsigned lds_off(const void* p) {
  return (unsigned)(size_t)(__attribute__((address_space(3))) const void*)p;
}

// Fused aux: [0,2048) gate, [2048,4096) W-transpose, [4096,6144) zero out[]
// (atomic-combine needs out pre-zeroed; stream-ordered before moe_gemm).
__global__ __launch_bounds__(256) void gate_transpose(
    const float* __restrict__ x, const float* __restrict__ gW,
    const float* __restrict__ gb, unsigned short* __restrict__ xb,
    int* __restrict__ eSel, float* __restrict__ wSel, int* __restrict__ cnt,
    const float* __restrict__ W, unsigned short* __restrict__ Wt,
    float4* __restrict__ outz)
{
  __shared__ __align__(16) float smem[NE * DIM];   // 32 KB union

  if (blockIdx.x >= 4096) {
    // ---- zero branch: 2048 blocks x 16 KB = 32 MB
    const float4 z = {0.f, 0.f, 0.f, 0.f};
    const unsigned base = (blockIdx.x - 4096) * 256 + threadIdx.x;
#pragma unroll
    for (int h = 0; h < 4; ++h)
      outz[base + h * 524288] = z;     // 2M float4 total
    return;
  }

  if (blockIdx.x >= 2048) {
    // ---- transpose_w: expert_W [e][d][f] fp32 -> Wt [e][f][d] bf16
    float (*t2)[65] = (float(*)[65])smem;          // 64 x 65 padded
    const int b  = blockIdx.x - 2048;
    const int e  = b >> 8;                 // 256 tiles per expert
    const int db = (b >> 4) & 15;          // d (k) block
    const int fb = b & 15;                 // f block
    const int d0 = db * 64, f0 = fb * 64;
    const int tid = threadIdx.x;
#pragma unroll
    for (int h = 0; h < 4; ++h) {
      const int idx = tid + h * 256;
      const int r = idx >> 4, c4 = idx & 15;
      float4 v = *(const float4*)&W[((size_t)e * DIM + d0 + r) * DIM + f0 + c4 * 4];
      t2[r][c4 * 4 + 0] = v.x;
      t2[r][c4 * 4 + 1] = v.y;
      t2[r][c4 * 4 + 2] = v.z;
      t2[r][c4 * 4 + 3] = v.w;
    }
    __syncthreads();
#pragma unroll
    for (int h = 0; h < 8; ++h) {
      const int o = tid + h * 256;
      const int f = o >> 5, k2 = (o & 31) * 2;
      const unsigned int lo = f2bf(t2[k2][f]);
      const unsigned int hi = f2bf(t2[k2 + 1][f]);
      *(unsigned int*)&Wt[((size_t)e * DIM + f0 + f) * DIM + d0 + k2] =
          lo | (hi << 16);
    }
    return;
  }

  // ---- gate branch: x row -> bf16 + gating dots (fp64 acc) + top-2 picks
  if (blockIdx.x == 0 && threadIdx.x < NE) cnt[threadIdx.x] = 0;

  float* gWs = smem;                // [e][d], 32 KB
#pragma unroll
  for (int h = 0; h < 8; ++h) {
    const int m = threadIdx.x + h * 256;       // float4 id over gW (2048)
    float4 v = ((const float4*)gW)[m];
    const int d = m >> 1, e0 = (m & 1) * 4;    // gW is [d][e]
    gWs[(e0 + 0) * DIM + d] = v.x;
    gWs[(e0 + 1) * DIM + d] = v.y;
    gWs[(e0 + 2) * DIM + d] = v.z;
    gWs[(e0 + 3) * DIM + d] = v.w;
  }
  __syncthreads();

  const int wave = threadIdx.x >> 6;
  const int lane = threadIdx.x & 63;
  const int t = blockIdx.x * 4 + wave;
  const float4* xrow = (const float4*)(x + (size_t)t * DIM);
  ushort4* xbrow = (ushort4*)(xb + (size_t)t * DIM);

  double acc[NE];
#pragma unroll
  for (int e = 0; e < NE; ++e) acc[e] = 0.0;

#pragma unroll
  for (int i = 0; i < 4; ++i) {
    const int j = i * 64 + lane;         // float4 index within row (0..255)
    float4 v = xrow[j];
    ushort4 pk;
    pk.x = f2bf(v.x); pk.y = f2bf(v.y); pk.z = f2bf(v.z); pk.w = f2bf(v.w);
    xbrow[j] = pk;
#pragma unroll
    for (int e = 0; e < NE; ++e) {
      float4 gv = *(const float4*)&gWs[e * DIM + j * 4];
      acc[e] += (double)v.x * (double)gv.x + (double)v.y * (double)gv.y
              + (double)v.z * (double)gv.z + (double)v.w * (double)gv.w;
    }
  }
#pragma unroll
  for (int off = 32; off > 0; off >>= 1) {
#pragma unroll
    for (int e = 0; e < NE; ++e)
      acc[e] += __shfl_xor(acc[e], off, 64);
  }

  if (lane == 0) {
    double s[NE];
#pragma unroll
    for (int e = 0; e < NE; ++e) {
      s[e] = acc[e] + (double)gb[e];
      if (s[e] < 1e-4) s[e] = 1e-4;     // clamp-min(EPS), TEMP=1
    }
    int e0 = 0;
    for (int e = 1; e < NE; ++e) if (s[e] > s[e0]) e0 = e;
    int e1 = (e0 == 0) ? 1 : 0;
    for (int e = 0; e < NE; ++e) if (e != e0 && s[e] > s[e1]) e1 = e;
    float m = (float)s[e0];
    float Z = 0.f, pf[NE];
#pragma unroll
    for (int e = 0; e < NE; ++e) { pf[e] = __expf((float)s[e] - m); Z += pf[e]; }
    float w0 = pf[e0] / Z; if (w0 < 0.1f) w0 = 0.1f;
    float w1 = pf[e1] / Z; if (w1 < 0.1f) w1 = 0.1f;
    const float inv = 0.5f / (w0 + w1);   // /total /K
    eSel[t * 2 + 0] = e0;
    eSel[t * 2 + 1] = e1;
    wSel[t * 2 + 0] = w0 * inv;
    wSel[t * 2 + 1] = w1 * inv;
  }
}

// Two-level scatter: LDS histogram per block, 8 global atomics per block.
__global__ __launch_bounds__(256) void scatter_kernel(
    const int* __restrict__ eSel, const float* __restrict__ wSel,
    int* __restrict__ cnt, int* __restrict__ listTok, float* __restrict__ listW)
{
  __shared__ int lcnt[NE];
  __shared__ int base[NE];
  const int tid = threadIdx.x;
  if (tid < NE) lcnt[tid] = 0;
  __syncthreads();

  const int t = blockIdx.x * 256 + tid;
  const int e0 = eSel[t * 2 + 0];
  const int e1 = eSel[t * 2 + 1];
  const float w0 = wSel[t * 2 + 0];
  const float w1 = wSel[t * 2 + 1];
  const int l0 = atomicAdd(&lcnt[e0], 1);
  const int l1 = atomicAdd(&lcnt[e1], 1);
  __syncthreads();
  if (tid < NE) base[tid] = atomicAdd(&cnt[tid], lcnt[tid]);
  __syncthreads();

  const int p0 = base[e0] + l0;
  listTok[e0 * TOK + p0] = t * 2 + 0;   // token*2 + slot
  listW [e0 * TOK + p0] = w0;
  const int p1 = base[e1] + l1;
  listTok[e1 * TOK + p1] = t * 2 + 1;
  listW [e1 * TOK + p1] = w1;
}

// ---------------------------------------------------------------------------
// R16 moe_gemm: R11 VERBATIM (the measured best: 65us, 256x128 tile, 4
// waves, 128x64 wave-tile, ring-3, counted vmcnt(6), asm ds_read) with two
// register-neutral changes:
//  1. SPLIT-WAIT CMP: reads ordered a0-3,b0-3 then a4-7; lgkmcnt(4) -> MFMA
//     mt0-3 (runs while a4-7 drain) -> lgkmcnt(0) -> MFMA mt4-7. Breaks the
//     per-wave all-reads->all-MFMA serialization (~576cy CU LDS drain before
//     any MFMA) without the E/O frag dbuf that spilled in R15 (0 extra regs).
//  2. Fused combine: epilogue unsafeAtomicAdd fp32 into pre-zeroed out
//     (native global_atomic_add_f32); kills the 96MB combine pass + launch.
// Ledger note: R14's premise was wrong - R11 already had counted vmcnt; its
// gap is read/MFMA serialization + DMA inflow, which #1 attacks.
// ---------------------------------------------------------------------------
#define WAITVM(n) asm volatile("s_waitcnt vmcnt(" #n ")" ::: "memory")

#define STG(kt, bs)                                                          \
  { const int off_ = (kt) * 32;                                              \
    gl_lds16(srcA0 + off_, &As[bs][w * 2048 + 0]);                           \
    gl_lds16(srcA1 + off_, &As[bs][w * 2048 + 512]);                         \
    gl_lds16(srcA2 + off_, &As[bs][w * 2048 + 1024]);                        \
    gl_lds16(srcA3 + off_, &As[bs][w * 2048 + 1536]);                        \
    gl_lds16(srcB0 + off_, &Bs[bs][w * 1024 + 0]);                           \
    gl_lds16(srcB1 + off_, &Bs[bs][w * 1024 + 512]); }

// A slot stride 16384 B, B slot stride 8192 B; fragment step 1024 B
#define CMP(bs)                                                              \
  { const unsigned aA = asOff + (unsigned)(bs) * 16384u + rdA2;              \
    const unsigned bA = bsOff + (unsigned)(bs) * 8192u + rdB2;               \
    bf16x8 a0,a1,a2,a3,a4,a5,a6,a7,b0,b1,b2,b3;                              \
    asm volatile(                                                            \
      "ds_read_b128 %0, %12 offset:0\n\t"                                    \
      "ds_read_b128 %1, %12 offset:1024\n\t"                                 \
      "ds_read_b128 %2, %12 offset:2048\n\t"                                 \
      "ds_read_b128 %3, %12 offset:3072\n\t"                                 \
      "ds_read_b128 %8, %13 offset:0\n\t"                                    \
      "ds_read_b128 %9, %13 offset:1024\n\t"                                 \
      "ds_read_b128 %10, %13 offset:2048\n\t"                                \
      "ds_read_b128 %11, %13 offset:3072\n\t"                                \
      "ds_read_b128 %4, %12 offset:4096\n\t"                                 \
      "ds_read_b128 %5, %12 offset:5120\n\t"                                 \
      "ds_read_b128 %6, %12 offset:6144\n\t"                                 \
      "ds_read_b128 %7, %12 offset:7168\n\t"                                 \
      "s_waitcnt lgkmcnt(4)"                                                 \
      : "=&v"(a0),"=&v"(a1),"=&v"(a2),"=&v"(a3),                             \
        "=&v"(a4),"=&v"(a5),"=&v"(a6),"=&v"(a7),                             \
        "=&v"(b0),"=&v"(b1),"=&v"(b2),"=&v"(b3)                              \
      : "v"(aA), "v"(bA)                                                     \
      : "memory");                                                           \
    __builtin_amdgcn_sched_barrier(0);                                       \
    bf16x8 afL[4] = {a0, a1, a2, a3};                                        \
    bf16x8 bfr[4] = {b0, b1, b2, b3};                                        \
    __builtin_amdgcn_s_setprio(1);                                           \
    _Pragma("unroll")                                                        \
    for (int mt = 0; mt < 4; ++mt)                                           \
      _Pragma("unroll")                                                      \
      for (int nt = 0; nt < 4; ++nt)                                         \
        acc[mt][nt] = __builtin_amdgcn_mfma_f32_16x16x32_bf16(               \
            afL[mt], bfr[nt], acc[mt][nt], 0, 0, 0);                         \
    __builtin_amdgcn_s_setprio(0);                                           \
    asm volatile("s_waitcnt lgkmcnt(0)" ::: "memory");                       \
    __builtin_amdgcn_sched_barrier(0);                                       \
    bf16x8 afH[4] = {a4, a5, a6, a7};                                        \
    __builtin_amdgcn_s_setprio(1);                                           \
    _Pragma("unroll")                                                        \
    for (int mt = 0; mt < 4; ++mt)                                           \
      _Pragma("unroll")                                                      \
      for (int nt = 0; nt < 4; ++nt)                                         \
        acc[mt + 4][nt] = __builtin_amdgcn_mfma_f32_16x16x32_bf16(           \
            afH[mt], bfr[nt], acc[mt + 4][nt], 0, 0, 0);                     \
    __builtin_amdgcn_s_setprio(0); }

__global__ __launch_bounds__(256, 2) void moe_gemm(
    const unsigned short* __restrict__ xb, const unsigned short* __restrict__ Wt,
    const float* __restrict__ eb, const int* __restrict__ cnt,
    const int* __restrict__ listTok, const float* __restrict__ listW,
    float* __restrict__ out)
{
  const int dId = blockIdx.x % NT;   // dId-major; NT%8==0 -> cT siblings share XCD
  const int cT  = blockIdx.x / NT;
  int e = -1, r0 = 0, rows = 0, accT = 0;
#pragma unroll
  for (int ee = 0; ee < NE; ++ee) {
    const int c = cnt[ee];
    const int nt = (c + 255) >> 8;
    if (dId >= accT && dId < accT + nt) {
      e = ee; r0 = (dId - accT) * 256;
      rows = c - r0; if (rows > 256) rows = 256;
    }
    accT += nt;
  }
  if (e < 0) return;   // block-uniform exit, before any barrier

  // ring-3: A 3x16KB, B 3x8KB, lists 2KB = 74KB -> 2 blocks/CU
  __shared__ __align__(16) unsigned short As[3][256 * 32];
  __shared__ __align__(16) unsigned short Bs[3][128 * 32];
  __shared__ int   tid_s[256];
  __shared__ float w_s[256];

  const int tid = threadIdx.x;
  if (tid < rows) {
    tid_s[tid] = listTok[e * TOK + r0 + tid];
    w_s[tid]   = listW [e * TOK + r0 + tid];
  } else {
    tid_s[tid] = 0;     // safe dummy row (token 0) — never stored
    w_s[tid]   = 0.0f;
  }
  __syncthreads();      // drains vmcnt -> counted region starts clean

  const int w    = tid >> 6;           // wave 0..3
  const int lane = tid & 63;
  const int qsrc = (lane & 3) ^ ((lane >> 3) & 3);
  const int lr   = lane >> 2;
  const unsigned short* srcA0 = xb + (size_t)(tid_s[w * 64 +  0 + lr] >> 1) * DIM + qsrc * 8;
  const unsigned short* srcA1 = xb + (size_t)(tid_s[w * 64 + 16 + lr] >> 1) * DIM + qsrc * 8;
  const unsigned short* srcA2 = xb + (size_t)(tid_s[w * 64 + 32 + lr] >> 1) * DIM + qsrc * 8;
  const unsigned short* srcA3 = xb + (size_t)(tid_s[w * 64 + 48 + lr] >> 1) * DIM + qsrc * 8;
  const unsigned short* srcB0 = Wt + ((size_t)e * DIM + cT * 128 + w * 32 +  0 + lr) * DIM + qsrc * 8;
  const unsigned short* srcB1 = Wt + ((size_t)e * DIM + cT * 128 + w * 32 + 16 + lr) * DIM + qsrc * 8;

  const int wr = w >> 1, wc = w & 1;   // 2M x 2N wave grid, 128x64 out each
  const int mrow = lane & 15;
  const int qg   = lane >> 4;
  const int s8   = (qg ^ ((mrow >> 1) & 3)) * 8;   // verified conflict-free
  const unsigned rdA2 = (unsigned)(((wr * 128 + mrow) * 32 + s8) * 2);  // bytes
  const unsigned rdB2 = (unsigned)(((wc * 64 + mrow) * 32 + s8) * 2);   // bytes
  const unsigned asOff = lds_off(&As[0][0]);
  const unsigned bsOff = lds_off(&Bs[0][0]);

  f32x4 acc[8][4];
#pragma unroll
  for (int i = 0; i < 8; ++i)
#pragma unroll
    for (int j = 0; j < 4; ++j)
      acc[i][j] = {0.f, 0.f, 0.f, 0.f};

  // prologue: tiles 0,1 -> slots 0,1 (12 calls); wait tile 0 (6 left)
  STG(0, 0);
  STG(1, 1);
  WAITVM(6);
  __builtin_amdgcn_s_barrier();

  int bC = 0, bS = 2;
#pragma unroll 1
  for (int kt = 0; kt < 30; ++kt) {    // steady state: stage kt+2, compute kt
    STG(kt + 2, bS);
    CMP(bC);
    WAITVM(6);                         // tile kt+1 resident; kt+2 in flight
    __builtin_amdgcn_s_barrier();
    bC = (bC == 2) ? 0 : bC + 1;
    bS = (bS == 2) ? 0 : bS + 1;
  }
  CMP(0);                              // tile 30 (slot 0)
  WAITVM(0);                           // drain tile 31
  __builtin_amdgcn_s_barrier();
  CMP(1);                              // tile 31 (slot 1)

  // epilogue: C/D map col=lane&15, row=(lane>>4)*4+r; fused combine via
  // native fp32 atomic add into pre-zeroed out. Both expert slots of a
  // token add into the same row. wgt already includes /total/K.
  const int colBase = cT * 128 + wc * 64 + mrow;
  float bias[4];
#pragma unroll
  for (int nt = 0; nt < 4; ++nt)
    bias[nt] = eb[(size_t)e * DIM + colBase + nt * 16];
#pragma unroll
  for (int mt = 0; mt < 8; ++mt) {
#pragma unroll
    for (int r = 0; r < 4; ++r) {
      const int rloc = wr * 128 + mt * 16 + (lane >> 4) * 4 + r;
      if (rloc < rows) {
        const int tk    = tid_s[rloc];
        const float wgt = w_s[rloc];
        float* dst = out + (size_t)(tk >> 1) * DIM;
#pragma unroll
        for (int nt = 0; nt < 4; ++nt)
          unsafeAtomicAdd(&dst[colBase + nt * 16],
                          wgt * (acc[mt][nt][r] + bias[nt]));
      }
    }
  }
}

extern "C" void kernel_launch(void* const* d_in, const int* in_sizes, int n_in,
                              void* d_out, int out_size, void* d_ws, size_t ws_size,
                              hipStream_t stream)
{
  const float* x  = (const float*)d_in[0];
  const float* gW = (const float*)d_in[1];
  const float* gb = (const float*)d_in[2];
  const float* eW = (const float*)d_in[3];
  const float* eb = (const float*)d_in[4];
  float* out = (float*)d_out;

  char* p = (char*)d_ws;
  unsigned short* xb = (unsigned short*)p;  p += (size_t)TOK * DIM * 2;       // 16 MB
  unsigned short* Wt = (unsigned short*)p;  p += (size_t)NE * DIM * DIM * 2;  // 16 MB
  char* scratch = p;                        p += (size_t)2 * TOK * DIM * 2;   // 32 MB
  int* cnt = (int*)p;                       p += 256;
  int* listTok = (int*)p;                   p += (size_t)NE * TOK * 4;
  float* listW = (float*)p;                 p += (size_t)NE * TOK * 4;

  int*   eSel = (int*)scratch;                      // TOK*2 ints = 64 KB
  float* wSel = (float*)(scratch + TOK * 8);        // TOK*2 floats = 64 KB

  gate_transpose<<<6144, 256, 0, stream>>>(x, gW, gb, xb, eSel, wSel, cnt,
                                           eW, Wt, (float4*)out);
  scatter_kernel<<<TOK / 256, 256, 0, stream>>>(eSel, wSel, cnt, listTok, listW);
  moe_gemm<<<NT * NCT, 256, 0, stream>>>(xb, Wt, eb, cnt, listTok, listW, out);
}